// Round 13
// baseline (418.581 us; speedup 1.0000x reference)
//
#include <hip/hip_runtime.h>

#define SCALE 22.627416997969522f
#define LNEPS 1e-5f
#define NTOK 2048
#define NBLK 256

using short8 = __attribute__((ext_vector_type(8))) short;
using f32x4  = __attribute__((ext_vector_type(4))) float;
typedef unsigned short u16;
using u16x4 = __attribute__((ext_vector_type(4))) u16;

static __device__ __forceinline__ u16 f2bf(float f){
  unsigned u = __builtin_bit_cast(unsigned, f);
  u += 0x7FFFu + ((u >> 16) & 1u);
  return (u16)(u >> 16);
}
static __device__ __forceinline__ float bf2f(u16 u){
  unsigned v = ((unsigned)u) << 16;
  return __builtin_bit_cast(float, v);
}

struct MegaArgs {
  const float* x; const int* A;
  const float* Wfc; const float* bfc;
  const float* Wq1; const float* bq1; const float* Wk1; const float* bk1;
  const float* Wv1; const float* bv1; const float* g1;  const float* be1;
  const float* Wq2; const float* bq2; const float* Wk2; const float* bk2;
  const float* Wv2; const float* bv2; const float* g2;  const float* be2;
  unsigned* ctr;
  float* embs; u16* embs_b; float* b1; u16* b1_b;
  u16* xb;
  u16* qb; u16* kb; u16* vb;        // layer1 (k,v head-major [8][2048][64])
  u16* qb2; u16* kb2; u16* vb2;     // layer2 (fresh buffers: no stale-cache reuse)
  u16* t_fc; u16* t_q1; u16* t_k1; u16* t_v1; u16* t_q2; u16* t_k2; u16* t_v2;
  float* out; float* att2;
};

// device-scope software grid barrier (all NBLK blocks co-resident by construction)
static __device__ __forceinline__ void gridbar(unsigned* ctr, unsigned target) {
  __syncthreads();
  if (threadIdx.x == 0) {
    __threadfence();  // release: drain writes to device coherence point
    __hip_atomic_fetch_add(ctr, 1u, __ATOMIC_ACQ_REL, __HIP_MEMORY_SCOPE_AGENT);
    while (__hip_atomic_load(ctr, __ATOMIC_ACQUIRE, __HIP_MEMORY_SCOPE_AGENT) < target)
      __builtin_amdgcn_s_sleep(2);
    __threadfence();  // acquire: invalidate local caches
  }
  __syncthreads();
}

// ---- one 64x64 GEMM tile on a 256-thread engine (t2 = local tid) ----
// mode 0: f32+bf16 dual store + relu (FC); 1: bf16 token-major (q);
// mode 2: bf16 head-major [h][n][64] (k, v).
static __device__ void gemm_engine(
    int t2, const u16* __restrict__ A, int K,
    const u16* __restrict__ T, const float* __restrict__ Bv,
    int bm, int ncol, int mode,
    float* __restrict__ Cf, u16* __restrict__ Cb,
    u16* As, u16* Bs)
{
  int wave = t2 >> 6, lane = t2 & 63;
  int wm = (wave >> 1) * 32, wn = (wave & 1) * 32;
  int lr = lane & 15, kg = lane >> 4;

  int o0 = t2*16, o1 = 4096 + t2*16;
  int r0 = o0 >> 7, cb0 = o0 & 127;
  int r1 = o1 >> 7, cb1 = o1 & 127;
  const char* Ag0 = (const char*)(A + (size_t)(bm*64 + r0) * K) + cb0;
  const char* Ag1 = (const char*)(A + (size_t)(bm*64 + r1) * K) + cb1;
  const char* Bg0 = (const char*)(T + (size_t)(ncol  + r0) * K) + cb0;
  const char* Bg1 = (const char*)(T + (size_t)(ncol  + r1) * K) + cb1;
  char* Ad0 = (char*)As + r0*128 + (cb0 ^ ((r0 & 7) << 4));
  char* Ad1 = (char*)As + r1*128 + (cb1 ^ ((r1 & 7) << 4));
  char* Bd0 = (char*)Bs + r0*128 + (cb0 ^ ((r0 & 7) << 4));
  char* Bd1 = (char*)Bs + r1*128 + (cb1 ^ ((r1 & 7) << 4));

  int sw = (lr & 7) << 4;
  const char* Afr0 = (const char*)As + (wm + lr) * 128;
  const char* Afr1 = (const char*)As + (wm + 16 + lr) * 128;
  const char* Bfr0 = (const char*)Bs + (wn + lr) * 128;
  const char* Bfr1 = (const char*)Bs + (wn + 16 + lr) * 128;

  f32x4 acc[2][2] = {};

  short8 pa0 = *(const short8*)Ag0;
  short8 pa1 = *(const short8*)Ag1;
  short8 pb0 = *(const short8*)Bg0;
  short8 pb1 = *(const short8*)Bg1;

  for (int k0 = 0; k0 < K; k0 += 64) {
    __syncthreads();
    *(short8*)Ad0 = pa0;  *(short8*)Ad1 = pa1;
    *(short8*)Bd0 = pb0;  *(short8*)Bd1 = pb1;
    __syncthreads();
    int kn = k0 + 64;
    if (kn < K) {
      pa0 = *(const short8*)(Ag0 + kn*2);
      pa1 = *(const short8*)(Ag1 + kn*2);
      pb0 = *(const short8*)(Bg0 + kn*2);
      pb1 = *(const short8*)(Bg1 + kn*2);
    }
#pragma unroll
    for (int ks = 0; ks < 2; ++ks) {
      int cb = (ks*64 + kg*16) ^ sw;
      short8 af0 = *(const short8*)(Afr0 + cb);
      short8 af1 = *(const short8*)(Afr1 + cb);
      short8 bf0 = *(const short8*)(Bfr0 + cb);
      short8 bf1 = *(const short8*)(Bfr1 + cb);
      acc[0][0] = __builtin_amdgcn_mfma_f32_16x16x32_bf16(af0, bf0, acc[0][0], 0, 0, 0);
      acc[0][1] = __builtin_amdgcn_mfma_f32_16x16x32_bf16(af0, bf1, acc[0][1], 0, 0, 0);
      acc[1][0] = __builtin_amdgcn_mfma_f32_16x16x32_bf16(af1, bf0, acc[1][0], 0, 0, 0);
      acc[1][1] = __builtin_amdgcn_mfma_f32_16x16x32_bf16(af1, bf1, acc[1][1], 0, 0, 0);
    }
  }

#pragma unroll
  for (int mi = 0; mi < 2; ++mi)
#pragma unroll
    for (int ni = 0; ni < 2; ++ni) {
      int col = ncol + wn + ni*16 + lr;
      float bia = Bv[col];
#pragma unroll
      for (int r = 0; r < 4; ++r) {
        int row = bm*64 + wm + mi*16 + kg*4 + r;
        float vv = acc[mi][ni][r] + bia;
        if (mode == 0) {
          vv = fmaxf(vv, 0.f);
          Cf[(size_t)row*512 + col] = vv;
          Cb[(size_t)row*512 + col] = f2bf(vv);
        } else if (mode == 1) {
          Cb[(size_t)row*512 + col] = f2bf(vv);
        } else {
          Cb[((size_t)(col >> 6) * NTOK + row) * 64 + (col & 63)] = f2bf(vv);
        }
      }
    }
}

// ---- attention for one token, 512 threads, wave = head; K/V head-major ----
template<int KLOC>
static __device__ void attn_token(
    int n, const u16* __restrict__ Qb, const u16* __restrict__ Kh,
    const u16* __restrict__ Vh, const int* __restrict__ Aidx,
    const float* __restrict__ resid,
    const float* __restrict__ gma, const float* __restrict__ bta,
    float* __restrict__ outp, u16* __restrict__ outb, float* __restrict__ attOut,
    float* o_s, int* idx_s, float* red_s)
{
  constexpr int NP = KLOC / 16;
  constexpr int NV = KLOC / 8;

  int t = threadIdx.x;
  int w = t >> 6;
  int lane = t & 63;

  __syncthreads();   // protect LDS reuse across token iterations
  if (t < KLOC) idx_s[t] = Aidx[(size_t)n*64 + t];
  __syncthreads();

  const u16* Kbase = Kh + (size_t)w * NTOK * 64;
  const u16* Vbase = Vh + (size_t)w * NTOK * 64;
  int jj = lane & 15, dq = lane >> 4;
  int jg = lane >> 3, dc = lane & 7;

  short8 vpre[NV];
#pragma unroll
  for (int p = 0; p < NV; ++p)
    vpre[p] = *(const short8*)(Vbase + (size_t)idx_s[p*8 + jg] * 64 + dc*8);

  float qreg[16];
  {
    const u16* qp = Qb + (size_t)n*512 + w*64 + dq*16;
    short8 qa = *(const short8*)qp;
    short8 qb2 = *(const short8*)(qp + 8);
#pragma unroll
    for (int i = 0; i < 8; ++i) {
      qreg[i]     = bf2f((u16)qa[i]);
      qreg[8 + i] = bf2f((u16)qb2[i]);
    }
  }

  float att[NP];
#pragma unroll
  for (int p = 0; p < NP; ++p) {
    const u16* kp = Kbase + (size_t)idx_s[p*16 + jj] * 64 + dq*16;
    short8 k0 = *(const short8*)kp;
    short8 k1 = *(const short8*)(kp + 8);
    float e = 0.f;
#pragma unroll
    for (int i = 0; i < 8; ++i) {
      e = fmaf(qreg[i],     bf2f((u16)k0[i]), e);
      e = fmaf(qreg[8 + i], bf2f((u16)k1[i]), e);
    }
    e += __shfl_xor(e, 16);
    e += __shfl_xor(e, 32);
    att[p] = e;
  }

  float mx = att[0];
#pragma unroll
  for (int p = 1; p < NP; ++p) mx = fmaxf(mx, att[p]);
  mx = fmaxf(mx, __shfl_xor(mx, 1)); mx = fmaxf(mx, __shfl_xor(mx, 2));
  mx = fmaxf(mx, __shfl_xor(mx, 4)); mx = fmaxf(mx, __shfl_xor(mx, 8));
  float s = 0.f;
#pragma unroll
  for (int p = 0; p < NP; ++p) { att[p] = __expf(att[p] - mx); s += att[p]; }
  s += __shfl_xor(s, 1); s += __shfl_xor(s, 2);
  s += __shfl_xor(s, 4); s += __shfl_xor(s, 8);
  float inv = 1.f / (s * SCALE);
#pragma unroll
  for (int p = 0; p < NP; ++p) att[p] *= inv;

  float vacc[8] = {0.f,0.f,0.f,0.f,0.f,0.f,0.f,0.f};
#pragma unroll
  for (int p = 0; p < NV; ++p) {
    float a = __shfl(att[p >> 1], (p & 1) * 8 + jg);
#pragma unroll
    for (int i = 0; i < 8; ++i)
      vacc[i] = fmaf(a, bf2f((u16)vpre[p][i]), vacc[i]);
  }
#pragma unroll
  for (int i = 0; i < 8; ++i) {
    vacc[i] += __shfl_xor(vacc[i], 8);
    vacc[i] += __shfl_xor(vacc[i], 16);
    vacc[i] += __shfl_xor(vacc[i], 32);
  }
  if (jg == 0) {
#pragma unroll
    for (int i = 0; i < 8; ++i)
      o_s[w*64 + dc*8 + i] = vacc[i];
  }
  __syncthreads();

  float x = o_s[t] + __builtin_nontemporal_load(resid + (size_t)n*512 + t);
  float su = x, sq = x * x;
  su += __shfl_xor(su, 1);  sq += __shfl_xor(sq, 1);
  su += __shfl_xor(su, 2);  sq += __shfl_xor(sq, 2);
  su += __shfl_xor(su, 4);  sq += __shfl_xor(sq, 4);
  su += __shfl_xor(su, 8);  sq += __shfl_xor(sq, 8);
  su += __shfl_xor(su, 16); sq += __shfl_xor(sq, 16);
  su += __shfl_xor(su, 32); sq += __shfl_xor(sq, 32);
  if (lane == 0) { red_s[w] = su; red_s[8 + w] = sq; }
  __syncthreads();
  float tot = 0.f, tots = 0.f;
#pragma unroll
  for (int i = 0; i < 8; ++i) { tot += red_s[i]; tots += red_s[8 + i]; }
  float mean = tot  * (1.0f/512.0f);
  float var  = tots * (1.0f/512.0f) - mean*mean;
  float rstd = rsqrtf(var + LNEPS);
  float y = (x - mean) * rstd * gma[t] + bta[t];
  __builtin_nontemporal_store(y, outp + (size_t)n*512 + t);
  if (outb != nullptr) outb[(size_t)n*512 + t] = f2bf(y);
  if (attOut != nullptr && t == 0) attOut[n] = 8.0f / SCALE;
}

// ================= the single persistent kernel =================
__global__ __launch_bounds__(512, 2) void mega_k(MegaArgs p)
{
  __shared__ u16   As[2][4096];
  __shared__ u16   Bs[2][4096];
  __shared__ float ttile[32*33];
  __shared__ float o_s[512];
  __shared__ int   idx_s[64];
  __shared__ float red_s[16];

  const int t = threadIdx.x;
  const int b = blockIdx.x;
  const int eng = t >> 8, t2 = t & 255;
  const int eid = b * 2 + eng;

  // ---- P0: cvt x -> xb ; transpose 7 weights -> t_* ----
  {
    int tid = b * 512 + t;
#pragma unroll
    for (int r = 0; r < 4; ++r) {
      int i = (tid + r * 131072) << 2;
      float4 v = *(const float4*)(p.x + i);
      u16x4 o;
      o[0] = f2bf(v.x); o[1] = f2bf(v.y); o[2] = f2bf(v.z); o[3] = f2bf(v.w);
      *(u16x4*)(p.xb + i) = o;
    }
  }
  {
    int tx = t & 31, ty = t >> 5;     // 32 x 16
    for (int j = 0; j < 8; ++j) {
      int tt = b + j * 256;           // 0..2047
      const float* W; u16* T; int K, N, bx, by;
      if (tt < 512) { W = p.Wfc; T = p.t_fc; K = 1024; N = 512; bx = tt & 15; by = tt >> 4; }
      else {
        int t3 = tt - 512; int z = t3 >> 8; int rr = t3 & 255;
        K = 512; N = 512; bx = rr & 15; by = rr >> 4;
        switch (z) {
          case 0: W = p.Wq1; T = p.t_q1; break;
          case 1: W = p.Wk1; T = p.t_k1; break;
          case 2: W = p.Wv1; T = p.t_v1; break;
          case 3: W = p.Wq2; T = p.t_q2; break;
          case 4: W = p.Wk2; T = p.t_k2; break;
          default: W = p.Wv2; T = p.t_v2; break;
        }
      }
      int n0 = bx * 32, k0 = by * 32;
      __syncthreads();
#pragma unroll
      for (int i = 0; i < 32; i += 16)
        ttile[(ty + i) * 33 + tx] = W[(size_t)(k0 + ty + i) * N + n0 + tx];
      __syncthreads();
#pragma unroll
      for (int i = 0; i < 32; i += 16)
        T[(size_t)(n0 + ty + i) * K + k0 + tx] = f2bf(ttile[tx * 33 + ty + i]);
    }
  }
  gridbar(p.ctr, NBLK);

  // ---- P1: FC — 256 tiles, engines 0..255 ----
  for (int tt = eid; tt < 256; tt += 512)
    gemm_engine(t2, p.xb, 1024, p.t_fc, p.bfc, tt & 31, (tt >> 5) * 64, 0,
                p.embs, p.embs_b, As[eng], Bs[eng]);
  gridbar(p.ctr, 2 * NBLK);

  // ---- P2: QKV1 — 768 tiles ----
  for (int tt = eid; tt < 768; tt += 512) {
    int sel = tt >> 8, w2 = tt & 255;
    const u16*   T = sel == 0 ? p.t_q1 : sel == 1 ? p.t_k1 : p.t_v1;
    const float* B = sel == 0 ? p.bq1  : sel == 1 ? p.bk1  : p.bv1;
    u16*         C = sel == 0 ? p.qb   : sel == 1 ? p.kb   : p.vb;
    gemm_engine(t2, p.embs_b, 512, T, B, w2 & 31, (w2 >> 5) * 64, sel == 0 ? 1 : 2,
                nullptr, C, As[eng], Bs[eng]);
  }
  gridbar(p.ctr, 3 * NBLK);

  // ---- P3: attn1 — 8 tokens per block ----
  for (int ii = 0; ii < 8; ++ii)
    attn_token<16>(b + ii * 256, p.qb, p.kb, p.vb, p.A, p.embs, p.g1, p.be1,
                   p.b1, p.b1_b, nullptr, o_s, idx_s, red_s);
  gridbar(p.ctr, 4 * NBLK);

  // ---- P4: QKV2 — 768 tiles (fresh buffers) ----
  for (int tt = eid; tt < 768; tt += 512) {
    int sel = tt >> 8, w2 = tt & 255;
    const u16*   T = sel == 0 ? p.t_q2 : sel == 1 ? p.t_k2 : p.t_v2;
    const float* B = sel == 0 ? p.bq2  : sel == 1 ? p.bk2  : p.bv2;
    u16*         C = sel == 0 ? p.qb2  : sel == 1 ? p.kb2  : p.vb2;
    gemm_engine(t2, p.b1_b, 512, T, B, w2 & 31, (w2 >> 5) * 64, sel == 0 ? 1 : 2,
                nullptr, C, As[eng], Bs[eng]);
  }
  gridbar(p.ctr, 5 * NBLK);

  // ---- P5: attn2 — 8 tokens per block ----
  for (int ii = 0; ii < 8; ++ii)
    attn_token<64>(b + ii * 256, p.qb2, p.kb2, p.vb2, p.A, p.b1, p.g2, p.be2,
                   p.out, nullptr, p.att2, o_s, idx_s, red_s);
}

extern "C" void kernel_launch(void* const* d_in, const int* in_sizes, int n_in,
                              void* d_out, int out_size, void* d_ws, size_t ws_size,
                              hipStream_t stream)
{
  MegaArgs p;
  p.x   = (const float*)d_in[0];
  p.A   = (const int*)  d_in[1];
  p.Wfc = (const float*)d_in[2];
  p.bfc = (const float*)d_in[3];
  p.Wq1 = (const float*)d_in[4];
  p.bq1 = (const float*)d_in[5];
  p.Wk1 = (const float*)d_in[6];
  p.bk1 = (const float*)d_in[7];
  p.Wv1 = (const float*)d_in[8];
  p.bv1 = (const float*)d_in[9];
  p.g1  = (const float*)d_in[10];
  p.be1 = (const float*)d_in[11];
  p.Wq2 = (const float*)d_in[12];
  p.bq2 = (const float*)d_in[13];
  p.Wk2 = (const float*)d_in[14];
  p.bk2 = (const float*)d_in[15];
  p.Wv2 = (const float*)d_in[16];
  p.bv2 = (const float*)d_in[17];
  p.g2  = (const float*)d_in[18];
  p.be2 = (const float*)d_in[19];

  char* ws = (char*)d_ws;
  const size_t SZ = (size_t)NTOK * 512;
  p.ctr    = (unsigned*)ws;  ws += 256;
  p.embs   = (float*)ws;     ws += SZ * 4;
  p.b1     = (float*)ws;     ws += SZ * 4;
  p.embs_b = (u16*)ws;       ws += SZ * 2;
  p.b1_b   = (u16*)ws;       ws += SZ * 2;
  p.qb     = (u16*)ws;       ws += SZ * 2;
  p.kb     = (u16*)ws;       ws += SZ * 2;
  p.vb     = (u16*)ws;       ws += SZ * 2;
  p.qb2    = (u16*)ws;       ws += SZ * 2;
  p.kb2    = (u16*)ws;       ws += SZ * 2;
  p.vb2    = (u16*)ws;       ws += SZ * 2;
  p.xb     = (u16*)ws;       ws += (size_t)NTOK * 1024 * 2;
  p.t_fc   = (u16*)ws;       ws += (size_t)512 * 1024 * 2;
  p.t_q1   = (u16*)ws;       ws += (size_t)512 * 512 * 2;
  p.t_k1   = (u16*)ws;       ws += (size_t)512 * 512 * 2;
  p.t_v1   = (u16*)ws;       ws += (size_t)512 * 512 * 2;
  p.t_q2   = (u16*)ws;       ws += (size_t)512 * 512 * 2;
  p.t_k2   = (u16*)ws;       ws += (size_t)512 * 512 * 2;
  p.t_v2   = (u16*)ws;       ws += (size_t)512 * 512 * 2;

  p.out  = (float*)d_out;
  p.att2 = p.out + SZ;

  hipMemsetAsync(p.ctr, 0, 256, stream);
  mega_k<<<dim3(NBLK), dim3(512), 0, stream>>>(p);
}

// Round 14
// 169.016 us; speedup vs baseline: 2.4766x; 2.4766x over previous
//
#include <hip/hip_runtime.h>

#define SCALE 22.627416997969522f
#define LNEPS 1e-5f
#define NTOK 2048

using short8 = __attribute__((ext_vector_type(8))) short;
using f32x4  = __attribute__((ext_vector_type(4))) float;
typedef unsigned short u16;
using u16x4 = __attribute__((ext_vector_type(4))) u16;

static __device__ __forceinline__ u16 f2bf(float f){
  unsigned u = __builtin_bit_cast(unsigned, f);
  u += 0x7FFFu + ((u >> 16) & 1u);
  return (u16)(u >> 16);
}
static __device__ __forceinline__ float bf2f(u16 u){
  unsigned v = ((unsigned)u) << 16;
  return __builtin_bit_cast(float, v);
}

// ---- prep (ONE launch): z<7 -> weight transpose to bf16 [N][K]; z==7 -> cvt x ----
__global__ __launch_bounds__(256) void prep_k(
    const float* __restrict__ x, u16* __restrict__ xb,
    const float* __restrict__ Wfc,
    const float* __restrict__ W1, const float* __restrict__ W2,
    const float* __restrict__ W3, const float* __restrict__ W4,
    const float* __restrict__ W5, const float* __restrict__ W6,
    u16* __restrict__ Tfc,
    u16* __restrict__ T1, u16* __restrict__ T2, u16* __restrict__ T3,
    u16* __restrict__ T4, u16* __restrict__ T5, u16* __restrict__ T6)
{
  int z = blockIdx.z;
  int t = threadIdx.x;
  if (z == 7) {
    // cvt: 512 (x,y) blocks x 256 thr x 16 elems = 2M
    int tid = (blockIdx.y * 16 + blockIdx.x) * 256 + t;
#pragma unroll
    for (int r = 0; r < 4; ++r) {
      int i = (tid + r * 131072) * 4;
      float4 v = *(const float4*)(x + i);
      u16x4 o;
      o[0] = f2bf(v.x); o[1] = f2bf(v.y); o[2] = f2bf(v.z); o[3] = f2bf(v.w);
      *(u16x4*)(xb + i) = o;
    }
    return;
  }
  const float* W; u16* T; int K, N;
  if (z == 0) { W = Wfc; T = Tfc; K = 1024; N = 512; }
  else {
    K = 512; N = 512;
    switch (z) {
      case 1: W = W1; T = T1; break;
      case 2: W = W2; T = T2; break;
      case 3: W = W3; T = T3; break;
      case 4: W = W4; T = T4; break;
      case 5: W = W5; T = T5; break;
      default: W = W6; T = T6; break;
    }
    if ((int)blockIdx.y >= 16) return;
  }
  __shared__ float tile[32][33];
  int n0 = blockIdx.x * 32, k0 = blockIdx.y * 32;
  int tx = t & 31, ty = t >> 5;  // 32 x 8
#pragma unroll
  for (int i = 0; i < 32; i += 8)
    tile[ty + i][tx] = W[(size_t)(k0 + ty + i) * N + n0 + tx];
  __syncthreads();
#pragma unroll
  for (int i = 0; i < 32; i += 8)
    T[(size_t)(n0 + ty + i) * K + k0 + tx] = f2bf(tile[tx][ty + i]);
}

// ---- GEMM: C = act(A_bf16[MxK] @ Wt_bf16[N][K]^T + bias), all-bf16 outputs ----
// LDS-staged 64x64 tile, BK=64, reg-prefetch, XOR-swizzled LDS.
// SPLIT3: sel0 -> token-major (q); sel1/2 -> head-major [h][n][64] (k, v).
template<bool RELU, bool SPLIT3>
__global__ __launch_bounds__(256) void gemm_k(
    const u16* __restrict__ A, int K,
    const u16* __restrict__ T0, const u16* __restrict__ T1, const u16* __restrict__ T2,
    const float* __restrict__ B0, const float* __restrict__ B1, const float* __restrict__ B2,
    u16* __restrict__ C0, u16* __restrict__ C1, u16* __restrict__ C2)
{
  __shared__ u16 As[64*64];
  __shared__ u16 Bs[64*64];

  int bm = blockIdx.x;
  int nglob = blockIdx.y * 64;
  int sel  = SPLIT3 ? (nglob >> 9) : 0;
  int ncol = nglob & 511;
  const u16*   T  = (sel==0) ? T0 : (sel==1) ? T1 : T2;
  const float* Bv = (sel==0) ? B0 : (sel==1) ? B1 : B2;

  int t = threadIdx.x;
  int wave = t >> 6, lane = t & 63;
  int wm = (wave >> 1) * 32, wn = (wave & 1) * 32;
  int lr = lane & 15, kg = lane >> 4;

  int o0 = t*16, o1 = 4096 + t*16;
  int r0 = o0 >> 7, cb0 = o0 & 127;
  int r1 = o1 >> 7, cb1 = o1 & 127;
  const char* Ag0 = (const char*)(A + (size_t)(bm*64 + r0) * K) + cb0;
  const char* Ag1 = (const char*)(A + (size_t)(bm*64 + r1) * K) + cb1;
  const char* Bg0 = (const char*)(T + (size_t)(ncol  + r0) * K) + cb0;
  const char* Bg1 = (const char*)(T + (size_t)(ncol  + r1) * K) + cb1;
  char* Ad0 = (char*)As + r0*128 + (cb0 ^ ((r0 & 7) << 4));
  char* Ad1 = (char*)As + r1*128 + (cb1 ^ ((r1 & 7) << 4));
  char* Bd0 = (char*)Bs + r0*128 + (cb0 ^ ((r0 & 7) << 4));
  char* Bd1 = (char*)Bs + r1*128 + (cb1 ^ ((r1 & 7) << 4));

  int sw = (lr & 7) << 4;
  const char* Afr0 = (const char*)As + (wm + lr) * 128;
  const char* Afr1 = (const char*)As + (wm + 16 + lr) * 128;
  const char* Bfr0 = (const char*)Bs + (wn + lr) * 128;
  const char* Bfr1 = (const char*)Bs + (wn + 16 + lr) * 128;

  f32x4 acc[2][2] = {};

  short8 pa0 = *(const short8*)Ag0;
  short8 pa1 = *(const short8*)Ag1;
  short8 pb0 = *(const short8*)Bg0;
  short8 pb1 = *(const short8*)Bg1;

  for (int k0 = 0; k0 < K; k0 += 64) {
    __syncthreads();
    *(short8*)Ad0 = pa0;  *(short8*)Ad1 = pa1;
    *(short8*)Bd0 = pb0;  *(short8*)Bd1 = pb1;
    __syncthreads();
    int kn = k0 + 64;
    if (kn < K) {
      pa0 = *(const short8*)(Ag0 + kn*2);
      pa1 = *(const short8*)(Ag1 + kn*2);
      pb0 = *(const short8*)(Bg0 + kn*2);
      pb1 = *(const short8*)(Bg1 + kn*2);
    }
#pragma unroll
    for (int ks = 0; ks < 2; ++ks) {
      int cb = (ks*64 + kg*16) ^ sw;
      short8 af0 = *(const short8*)(Afr0 + cb);
      short8 af1 = *(const short8*)(Afr1 + cb);
      short8 bf0 = *(const short8*)(Bfr0 + cb);
      short8 bf1 = *(const short8*)(Bfr1 + cb);
      acc[0][0] = __builtin_amdgcn_mfma_f32_16x16x32_bf16(af0, bf0, acc[0][0], 0, 0, 0);
      acc[0][1] = __builtin_amdgcn_mfma_f32_16x16x32_bf16(af0, bf1, acc[0][1], 0, 0, 0);
      acc[1][0] = __builtin_amdgcn_mfma_f32_16x16x32_bf16(af1, bf0, acc[1][0], 0, 0, 0);
      acc[1][1] = __builtin_amdgcn_mfma_f32_16x16x32_bf16(af1, bf1, acc[1][1], 0, 0, 0);
    }
  }

#pragma unroll
  for (int mi = 0; mi < 2; ++mi)
#pragma unroll
    for (int ni = 0; ni < 2; ++ni) {
      int col = ncol + wn + ni*16 + lr;
      float bia = Bv[col];
#pragma unroll
      for (int r = 0; r < 4; ++r) {
        int row = bm*64 + wm + mi*16 + kg*4 + r;
        float vv = acc[mi][ni][r] + bia;
        if (RELU) vv = fmaxf(vv, 0.f);
        if (SPLIT3 && sel != 0) {
          u16* C = (sel == 1) ? C1 : C2;                 // head-major
          C[((size_t)(col >> 6) * NTOK + row) * 64 + (col & 63)] = f2bf(vv);
        } else {
          C0[(size_t)row*512 + col] = f2bf(vv);          // token-major
        }
      }
    }
}

// ---- attention: 512 thr (8 waves), wave = head; K/V head-major [h][n][64].
// bf16 residual; out: f32 (attn2) and/or bf16 (attn1).
template<int KLOC>
__global__ __launch_bounds__(512, 4) void attn_k(
    const u16* __restrict__ Qb, const u16* __restrict__ Kh, const u16* __restrict__ Vh,
    const int* __restrict__ Aidx,
    const u16* __restrict__ residb,
    const float* __restrict__ gma, const float* __restrict__ bta,
    float* __restrict__ outp, u16* __restrict__ outb, float* __restrict__ attOut)
{
  constexpr int NP = KLOC / 16;
  constexpr int NV = KLOC / 8;

  __shared__ float o_s[512];
  __shared__ int   idx_s[KLOC];
  __shared__ float red_s[16];

  int n = blockIdx.x;
  int t = threadIdx.x;
  int w = t >> 6;
  int lane = t & 63;

  if (t < KLOC) idx_s[t] = Aidx[(size_t)n*64 + t];
  __syncthreads();

  const u16* Kbase = Kh + (size_t)w * NTOK * 64;
  const u16* Vbase = Vh + (size_t)w * NTOK * 64;
  int jj = lane & 15, dq = lane >> 4;
  int jg = lane >> 3, dc = lane & 7;

  short8 vpre[NV];
#pragma unroll
  for (int p = 0; p < NV; ++p)
    vpre[p] = *(const short8*)(Vbase + (size_t)idx_s[p*8 + jg] * 64 + dc*8);

  float qreg[16];
  {
    const u16* qp = Qb + (size_t)n*512 + w*64 + dq*16;
    short8 qa = *(const short8*)qp;
    short8 qb2 = *(const short8*)(qp + 8);
#pragma unroll
    for (int i = 0; i < 8; ++i) {
      qreg[i]     = bf2f((u16)qa[i]);
      qreg[8 + i] = bf2f((u16)qb2[i]);
    }
  }

  float att[NP];
#pragma unroll
  for (int p = 0; p < NP; ++p) {
    const u16* kp = Kbase + (size_t)idx_s[p*16 + jj] * 64 + dq*16;
    short8 k0 = *(const short8*)kp;
    short8 k1 = *(const short8*)(kp + 8);
    float e = 0.f;
#pragma unroll
    for (int i = 0; i < 8; ++i) {
      e = fmaf(qreg[i],     bf2f((u16)k0[i]), e);
      e = fmaf(qreg[8 + i], bf2f((u16)k1[i]), e);
    }
    e += __shfl_xor(e, 16);
    e += __shfl_xor(e, 32);
    att[p] = e;
  }

  float mx = att[0];
#pragma unroll
  for (int p = 1; p < NP; ++p) mx = fmaxf(mx, att[p]);
  mx = fmaxf(mx, __shfl_xor(mx, 1)); mx = fmaxf(mx, __shfl_xor(mx, 2));
  mx = fmaxf(mx, __shfl_xor(mx, 4)); mx = fmaxf(mx, __shfl_xor(mx, 8));
  float s = 0.f;
#pragma unroll
  for (int p = 0; p < NP; ++p) { att[p] = __expf(att[p] - mx); s += att[p]; }
  s += __shfl_xor(s, 1); s += __shfl_xor(s, 2);
  s += __shfl_xor(s, 4); s += __shfl_xor(s, 8);
  float inv = 1.f / (s * SCALE);
#pragma unroll
  for (int p = 0; p < NP; ++p) att[p] *= inv;

  float vacc[8] = {0.f,0.f,0.f,0.f,0.f,0.f,0.f,0.f};
#pragma unroll
  for (int p = 0; p < NV; ++p) {
    float a = __shfl(att[p >> 1], (p & 1) * 8 + jg);
#pragma unroll
    for (int i = 0; i < 8; ++i)
      vacc[i] = fmaf(a, bf2f((u16)vpre[p][i]), vacc[i]);
  }
#pragma unroll
  for (int i = 0; i < 8; ++i) {
    vacc[i] += __shfl_xor(vacc[i], 8);
    vacc[i] += __shfl_xor(vacc[i], 16);
    vacc[i] += __shfl_xor(vacc[i], 32);
  }
  if (jg == 0) {
#pragma unroll
    for (int i = 0; i < 8; ++i)
      o_s[w*64 + dc*8 + i] = vacc[i];
  }
  __syncthreads();

  // residual (bf16) + LayerNorm
  float x = o_s[t] + bf2f(residb[(size_t)n*512 + t]);
  float su = x, sq = x * x;
  su += __shfl_xor(su, 1);  sq += __shfl_xor(sq, 1);
  su += __shfl_xor(su, 2);  sq += __shfl_xor(sq, 2);
  su += __shfl_xor(su, 4);  sq += __shfl_xor(sq, 4);
  su += __shfl_xor(su, 8);  sq += __shfl_xor(sq, 8);
  su += __shfl_xor(su, 16); sq += __shfl_xor(sq, 16);
  su += __shfl_xor(su, 32); sq += __shfl_xor(sq, 32);
  if (lane == 0) { red_s[w] = su; red_s[8 + w] = sq; }
  __syncthreads();
  float tot = 0.f, tots = 0.f;
#pragma unroll
  for (int i = 0; i < 8; ++i) { tot += red_s[i]; tots += red_s[8 + i]; }
  float mean = tot  * (1.0f/512.0f);
  float var  = tots * (1.0f/512.0f) - mean*mean;
  float rstd = rsqrtf(var + LNEPS);
  float y = (x - mean) * rstd * gma[t] + bta[t];
  if (outp != nullptr) __builtin_nontemporal_store(y, outp + (size_t)n*512 + t);
  if (outb != nullptr) outb[(size_t)n*512 + t] = f2bf(y);
  if (attOut != nullptr && t == 0) attOut[n] = 8.0f / SCALE;
}

extern "C" void kernel_launch(void* const* d_in, const int* in_sizes, int n_in,
                              void* d_out, int out_size, void* d_ws, size_t ws_size,
                              hipStream_t stream)
{
  const float* x   = (const float*)d_in[0];
  const int*   A   = (const int*)  d_in[1];
  const float* Wfc = (const float*)d_in[2];
  const float* bfc = (const float*)d_in[3];
  const float* Wq1 = (const float*)d_in[4];
  const float* bq1 = (const float*)d_in[5];
  const float* Wk1 = (const float*)d_in[6];
  const float* bk1 = (const float*)d_in[7];
  const float* Wv1 = (const float*)d_in[8];
  const float* bv1 = (const float*)d_in[9];
  const float* g1  = (const float*)d_in[10];
  const float* be1 = (const float*)d_in[11];
  const float* Wq2 = (const float*)d_in[12];
  const float* bq2 = (const float*)d_in[13];
  const float* Wk2 = (const float*)d_in[14];
  const float* bk2 = (const float*)d_in[15];
  const float* Wv2 = (const float*)d_in[16];
  const float* bv2 = (const float*)d_in[17];
  const float* g2  = (const float*)d_in[18];
  const float* be2 = (const float*)d_in[19];

  char* ws = (char*)d_ws;
  const size_t SZ = (size_t)NTOK*512;
  u16* embs_b = (u16*)ws;                      ws += SZ*2;
  u16* b1_b   = (u16*)ws;                      ws += SZ*2;
  u16* qb     = (u16*)ws;                      ws += SZ*2;
  u16* kb     = (u16*)ws;                      ws += SZ*2;   // head-major [8][2048][64]
  u16* vb     = (u16*)ws;                      ws += SZ*2;   // head-major
  u16* xb     = (u16*)ws;                      ws += (size_t)NTOK*1024*2;
  u16* t_fc   = (u16*)ws;                      ws += (size_t)512*1024*2;
  u16* t_q1   = (u16*)ws;                      ws += (size_t)512*512*2;
  u16* t_k1   = (u16*)ws;                      ws += (size_t)512*512*2;
  u16* t_v1   = (u16*)ws;                      ws += (size_t)512*512*2;
  u16* t_q2   = (u16*)ws;                      ws += (size_t)512*512*2;
  u16* t_k2   = (u16*)ws;                      ws += (size_t)512*512*2;
  u16* t_v2   = (u16*)ws;                      ws += (size_t)512*512*2;

  float* out  = (float*)d_out;
  float* att2 = out + SZ;

  dim3 blk(256);
  // prep: cvt (z=7) + 7 weight transposes (z=0..6), ONE launch
  prep_k<<<dim3(16, 32, 8), blk, 0, stream>>>(x, xb,
      Wfc, Wq1, Wk1, Wv1, Wq2, Wk2, Wv2,
      t_fc, t_q1, t_k1, t_v1, t_q2, t_k2, t_v2);

  // FC: embs (bf16 only)
  gemm_k<true,false><<<dim3(32, 8), blk, 0, stream>>>(xb, 1024,
      t_fc, nullptr, nullptr, bfc, nullptr, nullptr, embs_b, nullptr, nullptr);
  // QKV1: q token-major, k/v head-major
  gemm_k<false,true><<<dim3(32, 24), blk, 0, stream>>>(embs_b, 512,
      t_q1, t_k1, t_v1, bq1, bk1, bv1, qb, kb, vb);
  // attn1 + resid(embs bf16) + LN -> b1 (bf16 only)
  attn_k<16><<<dim3(2048), dim3(512), 0, stream>>>(qb, kb, vb, A, embs_b,
      g1, be1, nullptr, b1_b, nullptr);
  // QKV2
  gemm_k<false,true><<<dim3(32, 24), blk, 0, stream>>>(b1_b, 512,
      t_q2, t_k2, t_v2, bq2, bk2, bv2, qb, kb, vb);
  // attn2 + resid(b1 bf16) + LN -> out (f32) + Att2
  attn_k<64><<<dim3(2048), dim3(512), 0, stream>>>(qb, kb, vb, A, b1_b,
      g2, be2, out, nullptr, att2);
}